// Round 3
// baseline (451.496 us; speedup 1.0000x reference)
//
#include <hip/hip_runtime.h>
#include <math.h>

// Problem constants (VQ2): B=16384, D_IN=512, H=64, C=256, K=2048
#define NB 16384
#define NDIN 512
#define NH 64
#define NC 256
#define NK 2048

typedef __bf16 bf16;
typedef __bf16 bf16x4 __attribute__((ext_vector_type(4)));
typedef __bf16 bf16x8 __attribute__((ext_vector_type(8)));
typedef float f32x4 __attribute__((ext_vector_type(4)));

__device__ __forceinline__ void gload_lds16(const bf16* g, bf16* l) {
  __builtin_amdgcn_global_load_lds(
      (const __attribute__((address_space(1))) void*)g,
      (__attribute__((address_space(3))) void*)l, 16, 0, 0);
}

__device__ __forceinline__ float bfhi(unsigned u) { return __uint_as_float(u & 0xffff0000u); }
__device__ __forceinline__ float bflo(unsigned u) { return __uint_as_float(u << 16); }

// ---------------------------------------------------------------------------
// fp32 -> bf16 cast (n4 = count/4)
// ---------------------------------------------------------------------------
__global__ __launch_bounds__(256) void cast_f2b(const float* __restrict__ in,
                                                bf16* __restrict__ out, int n4) {
  int i = blockIdx.x * 256 + threadIdx.x;
  if (i >= n4) return;
  float4 v = ((const float4*)in)[i];
  bf16x4 o;
  o[0] = (bf16)v.x; o[1] = (bf16)v.y; o[2] = (bf16)v.z; o[3] = (bf16)v.w;
  ((bf16x4*)out)[i] = o;
}

// ---------------------------------------------------------------------------
// W [K][N] fp32 -> Wt [N][K] bf16
// ---------------------------------------------------------------------------
__global__ __launch_bounds__(256) void transpose_cast(const float* __restrict__ W,
                                                      bf16* __restrict__ Wt, int K, int N) {
  int i = blockIdx.x * 256 + threadIdx.x;
  if (i >= K * N) return;
  int n = i / K, k = i - n * K;
  Wt[i] = (bf16)W[k * N + n];
}

// ---------------------------------------------------------------------------
// protos fp32 [NK][NC] -> bf16 + pn (norm of ROUNDED values); one wave/row
// ---------------------------------------------------------------------------
__global__ __launch_bounds__(256) void cast_protos(const float* __restrict__ P,
                                                   bf16* __restrict__ Pb,
                                                   float* __restrict__ pn) {
  int wave = (int)((blockIdx.x * 256 + threadIdx.x) >> 6);
  int lane = threadIdx.x & 63;
  if (wave >= NK) return;
  float4 v = ((const float4*)(P + (size_t)wave * NC))[lane];
  bf16x4 o;
  o[0] = (bf16)v.x; o[1] = (bf16)v.y; o[2] = (bf16)v.z; o[3] = (bf16)v.w;
  ((bf16x4*)(Pb + (size_t)wave * NC))[lane] = o;
  float s = 0.f;
#pragma unroll
  for (int j = 0; j < 4; ++j) {
    float f = (float)o[j];
    s = fmaf(f, f, s);
  }
  for (int off = 32; off > 0; off >>= 1) s += __shfl_xor(s, off);
  if (lane == 0) pn[wave] = s;
}

// ---------------------------------------------------------------------------
// Row squared-norms of bf16 [rows][NC]; one wave per row.
// ---------------------------------------------------------------------------
__global__ __launch_bounds__(256) void rownorm_bf(const bf16* __restrict__ X,
                                                  float* __restrict__ out, int rows) {
  int wave = (int)((blockIdx.x * 256 + threadIdx.x) >> 6);
  int lane = threadIdx.x & 63;
  if (wave >= rows) return;
  bf16x4 v = ((const bf16x4*)(X + (size_t)wave * NC))[lane];
  float s = 0.f;
#pragma unroll
  for (int j = 0; j < 4; ++j) {
    float f = (float)v[j];
    s = fmaf(f, f, s);
  }
  for (int off = 32; off > 0; off >>= 1) s += __shfl_xor(s, off);
  if (lane == 0) out[wave] = s;
}

// ---------------------------------------------------------------------------
// Column sums of mub [NB][NC] (bf16) -> colsum [NC] fp32 (atomic per column)
// ---------------------------------------------------------------------------
__global__ __launch_bounds__(256) void colsum_mu(const bf16* __restrict__ mub,
                                                 float* __restrict__ colsum) {
  const int c = threadIdx.x;
  const int r0 = blockIdx.x * 64;
  float acc = 0.f;
  for (int r = 0; r < 64; ++r) acc += (float)mub[(size_t)(r0 + r) * NC + c];
  atomicAdd(&colsum[c], acc);
}

// ---------------------------------------------------------------------------
// Fused MLP: mub = (relu(relu(x@W_emb+b_emb @W0+b0)@W1+b1))@W_mu + b_mu
// Block = 64 rows, 4 waves. Activations live in padded LDS (2-way bank max).
// ---------------------------------------------------------------------------
__global__ __launch_bounds__(256) void fused_mlp(
    const bf16* __restrict__ xb, const bf16* __restrict__ wembT,
    const bf16* __restrict__ w0T, const bf16* __restrict__ w1T,
    const bf16* __restrict__ wmuT,
    const float* __restrict__ b_emb, const float* __restrict__ b0,
    const float* __restrict__ b1, const float* __restrict__ b_mu,
    bf16* __restrict__ mub) {
  __shared__ __align__(16) bf16 Sa[64 * 40];   // staging A (pad 40)
  __shared__ __align__(16) bf16 Sb[64 * 40];   // staging B
  __shared__ __align__(16) bf16 H0[64 * 72];   // h0 (pad 72)
  __shared__ __align__(16) bf16 H1[64 * 72];   // h1
  __shared__ __align__(16) bf16 H2[64 * 264];  // h2 (pad 264)
  const int t = threadIdx.x, w = t >> 6, lane = t & 63;
  const int lm = lane & 15, kq = lane >> 4;
  const int bm = blockIdx.x * 64;
  const int r = t >> 2, seg = t & 3;
  f32x4 zero4 = {};
  f32x4 acc[4];

  // ---- phase A: h0 = x @ wembT^T + b_emb   (K=512, N=64, no relu)
#pragma unroll
  for (int mi = 0; mi < 4; ++mi) acc[mi] = zero4;
  for (int k0 = 0; k0 < NDIN; k0 += 32) {
    __syncthreads();
    *(uint4*)&Sa[r * 40 + seg * 8] = *(const uint4*)&xb[(size_t)(bm + r) * NDIN + k0 + seg * 8];
    *(uint4*)&Sb[r * 40 + seg * 8] = *(const uint4*)&wembT[(size_t)r * NDIN + k0 + seg * 8];
    __syncthreads();
    bf16x8 bfr = *(const bf16x8*)&Sb[(w * 16 + lm) * 40 + kq * 8];
#pragma unroll
    for (int mi = 0; mi < 4; ++mi) {
      bf16x8 afr = *(const bf16x8*)&Sa[(mi * 16 + lm) * 40 + kq * 8];
      acc[mi] = __builtin_amdgcn_mfma_f32_16x16x32_bf16(afr, bfr, acc[mi], 0, 0, 0);
    }
  }
  {
    const int col = w * 16 + lm;
    const float bv = b_emb[col];
#pragma unroll
    for (int mi = 0; mi < 4; ++mi)
#pragma unroll
      for (int rg = 0; rg < 4; ++rg)
        H0[(mi * 16 + kq * 4 + rg) * 72 + col] = (bf16)(acc[mi][rg] + bv);
  }
  __syncthreads();

  // ---- phase B: h1 = relu(H0 @ w0T^T + b0)   (K=64, N=64)
#pragma unroll
  for (int mi = 0; mi < 4; ++mi) acc[mi] = zero4;
  for (int k0 = 0; k0 < NH; k0 += 32) {
    __syncthreads();
    *(uint4*)&Sb[r * 40 + seg * 8] = *(const uint4*)&w0T[(size_t)r * NH + k0 + seg * 8];
    __syncthreads();
    bf16x8 bfr = *(const bf16x8*)&Sb[(w * 16 + lm) * 40 + kq * 8];
#pragma unroll
    for (int mi = 0; mi < 4; ++mi) {
      bf16x8 afr = *(const bf16x8*)&H0[(mi * 16 + lm) * 72 + k0 + kq * 8];
      acc[mi] = __builtin_amdgcn_mfma_f32_16x16x32_bf16(afr, bfr, acc[mi], 0, 0, 0);
    }
  }
  {
    const int col = w * 16 + lm;
    const float bv = b0[col];
#pragma unroll
    for (int mi = 0; mi < 4; ++mi)
#pragma unroll
      for (int rg = 0; rg < 4; ++rg)
        H1[(mi * 16 + kq * 4 + rg) * 72 + col] = (bf16)fmaxf(acc[mi][rg] + bv, 0.f);
  }
  __syncthreads();

  // ---- phase C: h2 = relu(H1 @ w1T^T + b1)   (K=64, N=256 in 4 groups)
  for (int ng = 0; ng < 4; ++ng) {
#pragma unroll
    for (int mi = 0; mi < 4; ++mi) acc[mi] = zero4;
    for (int k0 = 0; k0 < NH; k0 += 32) {
      __syncthreads();
      *(uint4*)&Sb[r * 40 + seg * 8] = *(const uint4*)&w1T[(size_t)(ng * 64 + r) * NH + k0 + seg * 8];
      __syncthreads();
      bf16x8 bfr = *(const bf16x8*)&Sb[(w * 16 + lm) * 40 + kq * 8];
#pragma unroll
      for (int mi = 0; mi < 4; ++mi) {
        bf16x8 afr = *(const bf16x8*)&H1[(mi * 16 + lm) * 72 + k0 + kq * 8];
        acc[mi] = __builtin_amdgcn_mfma_f32_16x16x32_bf16(afr, bfr, acc[mi], 0, 0, 0);
      }
    }
    const int col = ng * 64 + w * 16 + lm;
    const float bv = b1[col];
#pragma unroll
    for (int mi = 0; mi < 4; ++mi)
#pragma unroll
      for (int rg = 0; rg < 4; ++rg)
        H2[(mi * 16 + kq * 4 + rg) * 264 + col] = (bf16)fmaxf(acc[mi][rg] + bv, 0.f);
  }
  __syncthreads();

  // ---- phase D: mu = H2 @ wmuT^T + b_mu   (K=256, N=256 in 4 groups)
  for (int ng = 0; ng < 4; ++ng) {
#pragma unroll
    for (int mi = 0; mi < 4; ++mi) acc[mi] = zero4;
    for (int k0 = 0; k0 < NC; k0 += 32) {
      __syncthreads();
      *(uint4*)&Sb[r * 40 + seg * 8] = *(const uint4*)&wmuT[(size_t)(ng * 64 + r) * NC + k0 + seg * 8];
      __syncthreads();
      bf16x8 bfr = *(const bf16x8*)&Sb[(w * 16 + lm) * 40 + kq * 8];
#pragma unroll
      for (int mi = 0; mi < 4; ++mi) {
        bf16x8 afr = *(const bf16x8*)&H2[(mi * 16 + lm) * 264 + k0 + kq * 8];
        acc[mi] = __builtin_amdgcn_mfma_f32_16x16x32_bf16(afr, bfr, acc[mi], 0, 0, 0);
      }
    }
    const int col = ng * 64 + w * 16 + lm;
    const float bv = b_mu[col];
#pragma unroll
    for (int mi = 0; mi < 4; ++mi)
#pragma unroll
      for (int rg = 0; rg < 4; ++rg)
        mub[(size_t)(bm + mi * 16 + kq * 4 + rg) * NC + col] = (bf16)(acc[mi][rg] + bv);
  }
}

// ---------------------------------------------------------------------------
// S-GEMM (MFMA, XOR-swizzled LDS): S_bf16[b][k] = 2*mu·p - rn - pn, plus
// fused per-row argmax of (s_fp32 + gumbel) via packed u64 atomicMax.
// ---------------------------------------------------------------------------
__global__ __launch_bounds__(256) void gemm_S_mfma(
    const bf16* __restrict__ A, const bf16* __restrict__ Bt,
    const float* __restrict__ rn, const float* __restrict__ pn,
    const float* __restrict__ gum, bf16* __restrict__ S,
    unsigned long long* __restrict__ packed) {
  __shared__ __align__(16) bf16 As[128 * 32];
  __shared__ __align__(16) bf16 Bs[128 * 32];
  const int t = threadIdx.x;
  const int w = t >> 6, lane = t & 63;
  const int bm = blockIdx.x * 128, bn = blockIdx.y * 128;
  const int wm = (w >> 1) * 64, wn = (w & 1) * 64;
  const int lm = lane & 15, kq = lane >> 4;
  const int xorc = (lm & 3) ^ ((lm >> 2) & 3);
  const int pc8 = (kq ^ xorc) << 3;  // swizzled chunk byte/elem offset
  f32x4 acc[4][4] = {};
  for (int k0 = 0; k0 < NC; k0 += 32) {
    __syncthreads();
#pragma unroll
    for (int i = 0; i < 2; ++i) {
      int c = i * 256 + t;  // physical 16B slot; lds offset c*16 lane-contiguous
      int r = c >> 2, sg = c & 3;
      int kc = sg ^ (r & 3) ^ ((r >> 2) & 3);  // logical k-chunk for this slot
      gload_lds16(&A[(size_t)(bm + r) * NC + k0 + kc * 8], &As[c * 8]);
      gload_lds16(&Bt[(size_t)(bn + r) * NC + k0 + kc * 8], &Bs[c * 8]);
    }
    __syncthreads();
    bf16x8 a[4], b[4];
#pragma unroll
    for (int i = 0; i < 4; ++i) {
      a[i] = *(const bf16x8*)&As[(wm + i * 16 + lm) * 32 + pc8];
      b[i] = *(const bf16x8*)&Bs[(wn + i * 16 + lm) * 32 + pc8];
    }
#pragma unroll
    for (int mi = 0; mi < 4; ++mi)
#pragma unroll
      for (int ni = 0; ni < 4; ++ni)
        acc[mi][ni] = __builtin_amdgcn_mfma_f32_16x16x32_bf16(a[mi], b[ni], acc[mi][ni], 0, 0, 0);
  }
#pragma unroll
  for (int mi = 0; mi < 4; ++mi) {
#pragma unroll
    for (int rg = 0; rg < 4; ++rg) {
      const int row = bm + wm + mi * 16 + kq * 4 + rg;
      const float rv = rn[row];
      const float* grow = gum + (size_t)row * NK;
      unsigned long long best = 0ull;
#pragma unroll
      for (int ni = 0; ni < 4; ++ni) {
        const int col = bn + wn + ni * 16 + lm;
        float sv = 2.0f * acc[mi][ni][rg] - rv - pn[col];
        S[(size_t)row * NK + col] = (bf16)sv;
        float v = sv + grow[col];
        unsigned kb = __float_as_uint(v);
        kb = (kb & 0x80000000u) ? ~kb : (kb | 0x80000000u);
        unsigned long long pk = ((unsigned long long)kb << 32) | (unsigned)(~(unsigned)col);
        best = pk > best ? pk : best;
      }
      // reduce across the 16-lane lm group (rows are per-kq distinct)
#pragma unroll
      for (int off = 1; off < 16; off <<= 1) {
        unsigned lo = (unsigned)best, hi = (unsigned)(best >> 32);
        unsigned olo = __shfl_xor(lo, off), ohi = __shfl_xor(hi, off);
        unsigned long long o = ((unsigned long long)ohi << 32) | olo;
        if (o > best) best = o;
      }
      if (lm == 0) atomicMax(&packed[row], best);
    }
  }
}

// ---------------------------------------------------------------------------
// Row pass: softmax stats over bf16 S + proto gather via packed argmax.
// 16 rows/block, 4 rows/wave; per-wave LDS csp segments.
// ---------------------------------------------------------------------------
__global__ __launch_bounds__(256) void row_pass(
    const bf16* __restrict__ S, const unsigned long long* __restrict__ packed,
    const float* __restrict__ protos, float* __restrict__ out,
    float* __restrict__ csp, float* __restrict__ ml) {
  __shared__ float seg[4][NK];
  const int t = threadIdx.x, w = t >> 6, lane = t & 63;
  for (int k = lane; k < NK; k += 64) seg[w][k] = 0.f;
  for (int rr = 0; rr < 4; ++rr) {
    const int b = blockIdx.x * 16 + w * 4 + rr;
    const bf16* Srow = S + (size_t)b * NK;
    float s[32];
#pragma unroll
    for (int j = 0; j < 16; ++j) {
      unsigned u = *(const unsigned*)&Srow[j * 128 + lane * 2];
      s[2 * j] = bflo(u);
      s[2 * j + 1] = bfhi(u);
    }
    float m = -INFINITY;
#pragma unroll
    for (int j = 0; j < 32; ++j) m = fmaxf(m, s[j]);
    for (int off = 32; off > 0; off >>= 1) m = fmaxf(m, __shfl_xor(m, off));
    float Z = 0.f;
#pragma unroll
    for (int j = 0; j < 32; ++j) Z += expf(s[j] - m);
    for (int off = 32; off > 0; off >>= 1) Z += __shfl_xor(Z, off);
    const float mls = m + logf(Z);
    if (lane == 0) ml[b] = mls;
#pragma unroll
    for (int j = 0; j < 16; ++j) {
      float2* p = (float2*)&seg[w][j * 128 + lane * 2];
      float2 cur = *p;
      cur.x += expf(s[2 * j] - mls);
      cur.y += expf(s[2 * j + 1] - mls);
      *p = cur;
    }
    const unsigned col = ~(unsigned)(packed[b] & 0xffffffffull);
    ((float4*)(out + (size_t)b * NC))[lane] =
        ((const float4*)(protos + (size_t)col * NC))[lane];
  }
  __syncthreads();
  for (int k = t; k < NK; k += 256)
    atomicAdd(&csp[k], seg[0][k] + seg[1][k] + seg[2][k] + seg[3][k]);
}

// ---------------------------------------------------------------------------
// Finalize: closed-form csl + loss.
//   mean_b logprobs[.,k] = (2*colsum·p_k - rnsum - B*pn_k - mlsum)/B
// ---------------------------------------------------------------------------
__global__ __launch_bounds__(256) void finalize_v2(
    const float* __restrict__ csp, const float* __restrict__ colsum,
    const bf16* __restrict__ pb, const float* __restrict__ pn,
    const float* __restrict__ rn, const float* __restrict__ ml,
    float* __restrict__ out_loss) {
  const int t = threadIdx.x;
  __shared__ double sd[256];
  __shared__ float cs[256];
  double rs = 0.0, ms = 0.0;
  for (int i = t; i < NB; i += 256) {
    rs += (double)rn[i];
    ms += (double)ml[i];
  }
  cs[t] = colsum[t];
  sd[t] = rs;
  __syncthreads();
  for (int off = 128; off > 0; off >>= 1) {
    if (t < off) sd[t] += sd[t + off];
    __syncthreads();
  }
  const double rnsum = sd[0];
  __syncthreads();
  sd[t] = ms;
  __syncthreads();
  for (int off = 128; off > 0; off >>= 1) {
    if (t < off) sd[t] += sd[t + off];
    __syncthreads();
  }
  const double mlsum = sd[0];
  __syncthreads();
  double cap = 0.0, plp = 0.0;
  for (int k = t; k < NK; k += 256) {
    const bf16* pr = pb + (size_t)k * NC;
    float dot = 0.f;
    for (int c = 0; c < NC; c += 8) {
      bf16x8 v = *(const bf16x8*)&pr[c];
#pragma unroll
      for (int e = 0; e < 8; ++e) dot = fmaf(cs[c + e], (float)v[e], dot);
    }
    double csl = 2.0 * (double)dot - rnsum - (double)NB * (double)pn[k] - mlsum;
    double mlp = csl * (1.0 / (double)NB);
    double prior = (double)csp[k] * (1.0 / (double)NB) + 1e-6;
    double lp = log(prior);
    cap += prior * (lp - mlp);
    plp += prior * lp;
  }
  sd[t] = cap;
  __syncthreads();
  for (int off = 128; off > 0; off >>= 1) {
    if (t < off) sd[t] += sd[t + off];
    __syncthreads();
  }
  const double capT = sd[0];
  __syncthreads();
  sd[t] = plp;
  __syncthreads();
  for (int off = 128; off > 0; off >>= 1) {
    if (t < off) sd[t] += sd[t + off];
    __syncthreads();
  }
  if (t == 0) out_loss[0] = (float)(0.01 * capT + 0.001 * sd[0]);
}

// ---------------------------------------------------------------------------
extern "C" void kernel_launch(void* const* d_in, const int* in_sizes, int n_in,
                              void* d_out, int out_size, void* d_ws, size_t ws_size,
                              hipStream_t stream) {
  const float* x = (const float*)d_in[0];
  const float* gumbel = (const float*)d_in[1];
  const float* W_emb = (const float*)d_in[2];
  const float* b_emb = (const float*)d_in[3];
  const float* W0 = (const float*)d_in[4];
  const float* b0 = (const float*)d_in[5];
  const float* W1 = (const float*)d_in[6];
  const float* b1 = (const float*)d_in[7];
  const float* W_mu = (const float*)d_in[8];
  const float* b_mu = (const float*)d_in[9];
  // d_in[10]=W_var, d_in[11]=b_var unused (logvar dead downstream)
  const float* protos = (const float*)d_in[12];
  float* out = (float*)d_out;

  // workspace layout
  bf16* Sb16 = (bf16*)d_ws;                                   // [NB][NK] bf16
  float* rn = (float*)(Sb16 + (size_t)NB * NK);               // [NB]
  float* pn = rn + NB;                                        // [NK]
  float* ml = pn + NK;                                        // [NB]
  float* csp = ml + NB;                                       // [NK]   (zeroed)
  float* colsum = csp + NK;                                   // [NC]   (zeroed)
  unsigned long long* packed = (unsigned long long*)(colsum + NC);  // [NB] (zeroed)
  bf16* xb = (bf16*)(packed + NB);                            // [NB][NDIN]
  bf16* mub = xb + (size_t)NB * NDIN;                         // [NB][NC]
  bf16* pb = mub + (size_t)NB * NC;                           // [NK][NC]
  bf16* wembT = pb + (size_t)NK * NC;                         // [NH][NDIN]
  bf16* w0T = wembT + NDIN * NH;                              // [NH][NH]
  bf16* w1T = w0T + NH * NH;                                  // [NC][NH]
  bf16* wmuT = w1T + NH * NC;                                 // [NC][NC]

  hipMemsetAsync(csp, 0, (NK + NC) * sizeof(float) + NB * sizeof(unsigned long long), stream);

  dim3 blk(256);
  cast_f2b<<<(NB * NDIN / 4 + 255) / 256, blk, 0, stream>>>(x, xb, NB * NDIN / 4);
  transpose_cast<<<(NDIN * NH + 255) / 256, blk, 0, stream>>>(W_emb, wembT, NDIN, NH);
  transpose_cast<<<(NH * NH + 255) / 256, blk, 0, stream>>>(W0, w0T, NH, NH);
  transpose_cast<<<(NH * NC + 255) / 256, blk, 0, stream>>>(W1, w1T, NH, NC);
  transpose_cast<<<(NC * NC + 255) / 256, blk, 0, stream>>>(W_mu, wmuT, NC, NC);
  cast_protos<<<NK / 4, blk, 0, stream>>>(protos, pb, pn);

  fused_mlp<<<NB / 64, blk, 0, stream>>>(xb, wembT, w0T, w1T, wmuT,
                                         b_emb, b0, b1, b_mu, mub);
  rownorm_bf<<<NB / 4, blk, 0, stream>>>(mub, rn, NB);
  colsum_mu<<<NB / 64, blk, 0, stream>>>(mub, colsum);

  gemm_S_mfma<<<dim3(NB / 128, NK / 128), blk, 0, stream>>>(mub, pb, rn, pn,
                                                            gumbel, Sb16, packed);
  row_pass<<<NB / 16, blk, 0, stream>>>(Sb16, packed, protos, out, csp, ml);
  finalize_v2<<<1, blk, 0, stream>>>(csp, colsum, pb, pn, rn, ml,
                                     out + (size_t)NB * NC);
}